// Round 13
// baseline (2225.328 us; speedup 1.0000x reference)
//
#include <hip/hip_runtime.h>
#include <hip/hip_fp16.h>

#define N_   50000
#define E_   400000
#define ELG_ 1600000
#define B_   2000
#define F_   64
#define ED_  16
#define T_   6
#define SND_ 384

typedef long long ll;
typedef _Float16 f16x8 __attribute__((ext_vector_type(8)));
typedef float f32x4 __attribute__((ext_vector_type(4)));
typedef float fv4 __attribute__((ext_vector_type(4)));

__device__ inline float ldc(const float* p, ll i) { return p[i]; }
__device__ inline float ldc(const __half* p, ll i) { return __half2float(p[i]); }
__device__ inline void st1(float* p, float v) { *p = v; }
__device__ inline void st1(__half* p, float v) { *p = __float2half(v); }

// N-float vector load/store (f32: float4 chunks; f16: 8-half chunks)
template <int FPL>
__device__ inline void ldN(const float* p, float (&o)[FPL]) {
#pragma unroll
    for (int c = 0; c < FPL; c += 4) {
        fv4 v = *(const fv4*)(p + c);
        o[c] = v.x; o[c + 1] = v.y; o[c + 2] = v.z; o[c + 3] = v.w;
    }
}
template <int FPL>
__device__ inline void ldN(const __half* p, float (&o)[FPL]) {
#pragma unroll
    for (int c = 0; c < FPL; c += 8) {
        f16x8 raw = *(const f16x8*)(p + c);
#pragma unroll
        for (int i = 0; i < 8; i++) o[c + i] = (float)raw[i];
    }
}
template <int FPL>
__device__ inline void stN(float* p, const float (&v)[FPL]) {
#pragma unroll
    for (int c = 0; c < FPL; c += 4) {
        fv4 t; t.x = v[c]; t.y = v[c + 1]; t.z = v[c + 2]; t.w = v[c + 3];
        *(fv4*)(p + c) = t;
    }
}
template <int FPL>
__device__ inline void stN(__half* p, const float (&v)[FPL]) {
#pragma unroll
    for (int c = 0; c < FPL; c += 8) {
        f16x8 t;
#pragma unroll
        for (int i = 0; i < 8; i++) t[i] = (_Float16)v[c + i];
        *(f16x8*)(p + c) = t;
    }
}

// ---------------- CSR build ----------------
__global__ __launch_bounds__(256) void k_count(const int* __restrict__ ldst, int* __restrict__ cnt) {
    int i = blockIdx.x * 256 + threadIdx.x;
    if (i < ELG_) atomicAdd(&cnt[ldst[i]], 1);
}

__global__ __launch_bounds__(256) void k_scan1(const int* __restrict__ cnt, int* __restrict__ rowptr,
                                               int* __restrict__ bsum) {
    __shared__ int s[256];
    int tid = threadIdx.x;
    int i = blockIdx.x * 256 + tid;
    int v = (i < E_) ? cnt[i] : 0;
    s[tid] = v;
    __syncthreads();
    for (int off = 1; off < 256; off <<= 1) {
        int t = (tid >= off) ? s[tid - off] : 0;
        __syncthreads();
        s[tid] += t;
        __syncthreads();
    }
    if (i < E_) rowptr[i] = s[tid] - v;
    if (tid == 255) bsum[blockIdx.x] = s[255];
}

__global__ __launch_bounds__(256) void k_scan2(int* __restrict__ bsum, int nb) {
    __shared__ int s[256];
    __shared__ int carry_s;
    int tid = threadIdx.x;
    if (tid == 0) carry_s = 0;
    __syncthreads();
    for (int base = 0; base < nb; base += 256) {
        int i = base + tid;
        int v = (i < nb) ? bsum[i] : 0;
        s[tid] = v;
        __syncthreads();
        for (int off = 1; off < 256; off <<= 1) {
            int t = (tid >= off) ? s[tid - off] : 0;
            __syncthreads();
            s[tid] += t;
            __syncthreads();
        }
        int c = carry_s;
        if (i < nb) bsum[i] = s[tid] - v + c;
        __syncthreads();
        if (tid == 0) carry_s = c + s[255];
        __syncthreads();
    }
}

__global__ __launch_bounds__(256) void k_scan3(int* __restrict__ rowptr, const int* __restrict__ bsum) {
    int i = blockIdx.x * 256 + threadIdx.x;
    if (i < E_) rowptr[i] += bsum[i >> 8];
    if (i == 0) rowptr[E_] = ELG_;
}

__global__ __launch_bounds__(256) void k_fill(const int* __restrict__ lsrc, const int* __restrict__ ldst,
                                              const int* __restrict__ rowptr, int* __restrict__ cursor,
                                              int* __restrict__ csr) {
    int i = blockIdx.x * 256 + threadIdx.x;
    if (i < ELG_) {
        int d = ldst[i];
        int pos = atomicAdd(&cursor[d], 1);
        csr[rowptr[d] + pos] = lsrc[i];
    }
}

__global__ __launch_bounds__(256) void k_bptr(const int* __restrict__ eib, int* __restrict__ bptr) {
    int b = blockIdx.x * 256 + threadIdx.x;
    if (b > B_) return;
    int lo = 0, hi = E_;
    while (lo < hi) {
        int mid = (lo + hi) >> 1;
        if (eib[mid] < b) lo = mid + 1; else hi = mid;
    }
    bptr[b] = lo;
}

// ---------------- node projections ----------------
__global__ __launch_bounds__(256) void k_xuv(const float* __restrict__ x,
                                             const float* __restrict__ Wu, const float* __restrict__ Wv,
                                             float* __restrict__ xu, float* __restrict__ xv) {
    __shared__ float wus[64 * 65];
    __shared__ float wvs[64 * 65];
    __shared__ float xs[16][64];
    int tid = threadIdx.x;
    for (int i = tid; i < 4096; i += 256) {
        int f = i >> 6, k = i & 63;
        wus[k * 65 + f] = Wu[i];
        wvs[k * 65 + f] = Wv[i];
    }
    int r0 = blockIdx.x * 16;
    for (int i = tid; i < 16 * 64; i += 256) {
        int r = i >> 6, j = i & 63;
        int row = r0 + r;
        xs[r][j] = (row < N_) ? x[(ll)row * 64 + j] : 0.f;
    }
    __syncthreads();
    int j = tid & 63, lr0 = tid >> 6;
    float su[4] = {0, 0, 0, 0}, sv[4] = {0, 0, 0, 0};
    for (int k = 0; k < 64; k++) {
        float wu = wus[k * 65 + j];
        float wv = wvs[k * 65 + j];
#pragma unroll
        for (int r = 0; r < 4; r++) {
            float xr = xs[lr0 + r * 4][k];
            su[r] += xr * wu;
            sv[r] += xr * wv;
        }
    }
#pragma unroll
    for (int r = 0; r < 4; r++) {
        int row = r0 + lr0 + r * 4;
        if (row < N_) {
            xu[(ll)row * 64 + j] = su[r];
            xv[(ll)row * 64 + j] = sv[r];
        }
    }
}

// ---------------- edge features -> state buffer (o_0 = ef) ----------------
template <typename ET>
__global__ __launch_bounds__(256) void k_ef(const float* __restrict__ xu, const float* __restrict__ xv,
                                            const float* __restrict__ ea, const float* __restrict__ We,
                                            const int* __restrict__ src, const int* __restrict__ dst,
                                            ET* __restrict__ ef) {
    __shared__ float wes[16 * 65];
    int tid = threadIdx.x;
    for (int i = tid; i < 1024; i += 256) {
        wes[(i & 15) * 65 + (i >> 4)] = We[i];
    }
    __syncthreads();
    int wid = tid >> 6, f = tid & 63;
    ll e0 = (ll)blockIdx.x * 16;
#pragma unroll
    for (int r = 0; r < 4; r++) {
        ll e = e0 + wid + r * 4;
        if (e >= E_) return;
        int s = src[e], d = dst[e];
        float v = xu[(ll)s * 64 + f] + xv[(ll)d * 64 + f];
#pragma unroll
        for (int k = 0; k < 16; k++) v += ea[e * 16 + k] * wes[k * 65 + f];
        st1(&ef[e * 64 + f], v * (1.0f / 3.0f));
    }
}

// ------ vectorized fused seg step; 4-way unrolled dual-accumulator gather ------
// WOUT: write o to nxt.  WXC: GraphConv logit xc.  ACC: 1 = outw = w*o, 2 = outw += w*o.
template <typename T, typename OT, bool WOUT, bool WXC, int ACC>
__global__ __launch_bounds__(256) void k_segv(
    const T* __restrict__ state, T* __restrict__ nxt, OT* __restrict__ outw,
    const float* __restrict__ xu, const float* __restrict__ xv,
    const float* __restrict__ ea, const float* __restrict__ We,
    const int* __restrict__ esrc, const int* __restrict__ edst,
    const int* __restrict__ rowptr, const int* __restrict__ csr,
    float* __restrict__ xc, const float* __restrict__ w_rel,
    const float* __restrict__ b_rel, const float* __restrict__ w_root,
    const float* __restrict__ scores, const int* __restrict__ eib, int tslot)
{
    constexpr int FPL = 16 / sizeof(T);
    constexpr int LPR = F_ / FPL;
    constexpr int RPB = 256 / LPR;
    constexpr bool EF = WOUT || (ACC > 0);
    __shared__ float wes[16 * 65];
    int tid = threadIdx.x;
    if (EF) {
        for (int i = tid; i < 1024; i += 256)
            wes[(i & 15) * 65 + (i >> 4)] = We[i];
        __syncthreads();
    }
    int sub = tid % LPR;
    int r   = tid / LPR;
    ll d = (ll)blockIdx.x * RPB + r;
    int f0 = sub * FPL;
    int p0 = rowptr[d], p1 = rowptr[d + 1];
    float acc[FPL], acc2[FPL];
#pragma unroll
    for (int j = 0; j < FPL; j++) { acc[j] = 0.f; acc2[j] = 0.f; }
    int p = p0;
    for (; p + 4 <= p1; p += 4) {
        int s0 = csr[p], s1 = csr[p + 1], s2 = csr[p + 2], s3 = csr[p + 3];
        float v0[FPL], v1[FPL], v2[FPL], v3[FPL];
        ldN<FPL>(&state[(ll)s0 * F_ + f0], v0);
        ldN<FPL>(&state[(ll)s1 * F_ + f0], v1);
        ldN<FPL>(&state[(ll)s2 * F_ + f0], v2);
        ldN<FPL>(&state[(ll)s3 * F_ + f0], v3);
#pragma unroll
        for (int j = 0; j < FPL; j++) { acc[j] += v0[j] + v2[j]; acc2[j] += v1[j] + v3[j]; }
    }
    for (; p + 2 <= p1; p += 2) {
        int s0 = csr[p], s1 = csr[p + 1];
        float v0[FPL], v1[FPL];
        ldN<FPL>(&state[(ll)s0 * F_ + f0], v0);
        ldN<FPL>(&state[(ll)s1 * F_ + f0], v1);
#pragma unroll
        for (int j = 0; j < FPL; j++) { acc[j] += v0[j]; acc2[j] += v1[j]; }
    }
    if (p < p1) {
        int s0 = csr[p];
        float v0[FPL];
        ldN<FPL>(&state[(ll)s0 * F_ + f0], v0);
#pragma unroll
        for (int j = 0; j < FPL; j++) acc[j] += v0[j];
    }
#pragma unroll
    for (int j = 0; j < FPL; j++) acc[j] += acc2[j];
    if (EF) {
        int se = esrc[d], de = edst[d];
        float o[FPL], xuv[FPL], xvv[FPL];
        ldN<FPL>(&xu[(ll)se * 64 + f0], xuv);
        ldN<FPL>(&xv[(ll)de * 64 + f0], xvv);
#pragma unroll
        for (int j = 0; j < FPL; j++) o[j] = xuv[j] + xvv[j];
#pragma unroll
        for (int k = 0; k < 16; k++) {
            float eav = ea[d * 16 + k];
#pragma unroll
            for (int j = 0; j < FPL; j++) o[j] += eav * wes[k * 65 + f0 + j];
        }
#pragma unroll
        for (int j = 0; j < FPL; j++) o[j] = o[j] * (1.0f / 3.0f) + acc[j];
        if (WOUT) stN<FPL>(&nxt[(ll)d * F_ + f0], o);
        if (ACC > 0) {
            float w = scores[eib[d] * 6 + tslot];
            float ow[FPL];
            if (ACC == 2) ldN<FPL>(&outw[(ll)d * F_ + f0], ow);
            else {
#pragma unroll
                for (int j = 0; j < FPL; j++) ow[j] = 0.f;
            }
#pragma unroll
            for (int j = 0; j < FPL; j++) ow[j] += w * o[j];
            stN<FPL>(&outw[(ll)d * F_ + f0], ow);
        }
    }
    if (WXC) {
        float ov[FPL];
        ldN<FPL>(&state[(ll)d * F_ + f0], ov);
        float part = 0.f;
#pragma unroll
        for (int j = 0; j < FPL; j++)
            part += acc[j] * w_rel[f0 + j] + ov[j] * w_root[f0 + j];
#pragma unroll
        for (int off = LPR / 2; off; off >>= 1) part += __shfl_xor(part, off, 64);
        if (sub == 0) xc[d] = part + b_rel[0];
    }
}

// ---------------- fold o_5,o_6 into outw: outw = s4*o5 + s5*o6 ----------------
template <typename TA, typename TB, typename OT>
__global__ __launch_bounds__(256) void k_comb(const TA* __restrict__ o6, const TB* __restrict__ o5,
                                              OT* __restrict__ outw, const float* __restrict__ scores,
                                              const int* __restrict__ eib) {
    ll i = (ll)blockIdx.x * 256 + threadIdx.x;
    if (i >= (ll)E_ * 64) return;
    int e = (int)(i >> 6);
    int b = eib[e];
    float v = scores[b * 6 + 4] * ldc(o5, i) + scores[b * 6 + 5] * ldc(o6, i);
    st1(&outw[i], v);
}

// ---------------- per-batch softmax + attention pool + tanh(g@Wg^T+bg) ----------------
template <typename ST>
__global__ __launch_bounds__(256) void k_pool(const float* __restrict__ xc, const ST* __restrict__ out_t,
                                              const int* __restrict__ bptr, const float* __restrict__ Wg,
                                              const float* __restrict__ bg, float* __restrict__ gouts,
                                              int tslot) {
    int b = blockIdx.x;
    int tid = threadIdx.x;
    int p0 = bptr[b], p1 = bptr[b + 1];
    __shared__ float red[256];
    __shared__ float gsh[64];
    float m = -1e30f;
    for (int i = p0 + tid; i < p1; i += 256) m = fmaxf(m, xc[i]);
    red[tid] = m;
    __syncthreads();
    for (int o = 128; o; o >>= 1) { if (tid < o) red[tid] = fmaxf(red[tid], red[tid + o]); __syncthreads(); }
    m = red[0];
    __syncthreads();
    float ss = 0.f;
    for (int i = p0 + tid; i < p1; i += 256) ss += __expf(xc[i] - m);
    red[tid] = ss;
    __syncthreads();
    for (int o = 128; o; o >>= 1) { if (tid < o) red[tid] += red[tid + o]; __syncthreads(); }
    float inv = 1.0f / (red[0] + 1e-16f);
    __syncthreads();
    int lane = tid & 63, grp = tid >> 6;
    float acc = 0.f;
    for (int e = p0 + grp; e < p1; e += 4) {
        float w = __expf(xc[e] - m) * inv;
        acc += ldc(out_t, (ll)e * 64 + lane) * w;
    }
    red[tid] = acc;
    __syncthreads();
    if (tid < 64) gsh[tid] = red[tid] + red[tid + 64] + red[tid + 128] + red[tid + 192];
    __syncthreads();
    if (tid < 64) {
        float z = bg[tid];
#pragma unroll 8
        for (int k = 0; k < 64; k++) z += gsh[k] * Wg[tid * 64 + k];
        gouts[((ll)b * T_ + tslot) * 64 + tid] = tanhf(z);
    }
}

// ---------------- per-batch scores over T ----------------
__global__ __launch_bounds__(64) void k_scores(const float* __restrict__ gouts, const float* __restrict__ a,
                                               const float* __restrict__ ab, float* __restrict__ scores) {
    int b = blockIdx.x, f = threadIdx.x;
    float lg[6];
#pragma unroll
    for (int t = 0; t < 6; t++) {
        float v = gouts[((ll)b * T_ + t) * 64 + f] * a[f * 6 + t];
#pragma unroll
        for (int o = 32; o; o >>= 1) v += __shfl_xor(v, o, 64);
        lg[t] = v + ab[t];
    }
    float m = lg[0];
#pragma unroll
    for (int t = 1; t < 6; t++) m = fmaxf(m, lg[t]);
    float s = 0.f;
#pragma unroll
    for (int t = 0; t < 6; t++) { lg[t] = __expf(lg[t] - m); s += lg[t]; }
    if (f == 0) {
        float inv = 1.0f / s;
#pragma unroll
        for (int t = 0; t < 6; t++) scores[b * 6 + t] = lg[t] * inv;
    }
}

__global__ __launch_bounds__(256) void k_copy(const float* __restrict__ in, float* __restrict__ out, int n) {
    int i = blockIdx.x * 256 + threadIdx.x;
    if (i < n) out[i] = in[i];
}

__global__ __launch_bounds__(256) void k_zero(float* __restrict__ out, int n) {
    int i = blockIdx.x * 256 + threadIdx.x;
    if (i < n) out[i] = 0.f;
}

__global__ __launch_bounds__(256) void k_f2h(const float* __restrict__ in, __half* __restrict__ out, int n) {
    int i = blockIdx.x * 256 + threadIdx.x;
    if (i < n) out[i] = __float2half(in[i]);
}

// ---------------- final scatter: h[dst[e]] += outw[e]; 64 lanes = 1 row (coalesced atomics) ----------------
template <typename OT>
__global__ __launch_bounds__(256) void k_scatter(const OT* __restrict__ outw, const int* __restrict__ dst,
                                                 float* __restrict__ h) {
    ll i = (ll)blockIdx.x * 256 + threadIdx.x;
    if (i >= (ll)E_ * 64) return;
    int e = (int)(i >> 6), f = (int)(i & 63);
    atomicAdd(&h[(ll)dst[e] * 64 + f], ldc(outw, i));
}

// ---------------- wide-N MFMA f16 GEMM: block = 64 rows x NFRAG*16 cols (A read once) ----------------
template <int NFRAG, int MODE, typename CT>  // MODE 0: relu(z)  1: (z + R)/2
__global__ __launch_bounds__(256) void k_gemm_w(
    const __half* __restrict__ Ah, const __half* __restrict__ Wh,
    const float* __restrict__ bias, const __half* __restrict__ R,
    CT* __restrict__ C, int M, int K)
{
    constexpr int NC = NFRAG * 16;
    __shared__ _Float16 As[64][40];
    __shared__ _Float16 Ws[NC][40];
    int tid = threadIdx.x;
    int m0 = blockIdx.x * 64;
    int wv = tid >> 6, lane = tid & 63;
    int srow = tid >> 2, skq = tid & 3;
    f32x4 acc[NFRAG] = {};
    const int arow = m0 + srow;
    for (int k0 = 0; k0 < K; k0 += 32) {
        f16x8 a8 = {};
        if (arow < M) a8 = *(const f16x8*)&Ah[(ll)arow * K + k0 + skq * 8];
        *(f16x8*)&As[srow][skq * 8] = a8;
        for (int i = tid; i < NC * 4; i += 256) {
            int wrow = i >> 2, wkq = i & 3;
            f16x8 w8 = *(const f16x8*)&Wh[(ll)wrow * K + k0 + wkq * 8];
            *(f16x8*)&Ws[wrow][wkq * 8] = w8;
        }
        __syncthreads();
        f16x8 af = *(const f16x8*)&As[wv * 16 + (lane & 15)][(lane >> 4) * 8];
#pragma unroll
        for (int nt = 0; nt < NFRAG; nt++) {
            f16x8 bf = *(const f16x8*)&Ws[nt * 16 + (lane & 15)][(lane >> 4) * 8];
            acc[nt] = __builtin_amdgcn_mfma_f32_16x16x32_f16(af, bf, acc[nt], 0, 0, 0);
        }
        __syncthreads();
    }
    int colb = lane & 15;
    int row0 = m0 + wv * 16 + (lane >> 4) * 4;
#pragma unroll
    for (int nt = 0; nt < NFRAG; nt++) {
        int col = nt * 16 + colb;
#pragma unroll
        for (int rg = 0; rg < 4; rg++) {
            int row = row0 + rg;
            if (row >= M) continue;
            float z = acc[nt][rg] + bias[col];
            float o;
            if (MODE == 0) o = fmaxf(z, 0.f);
            else o = (z + __half2float(R[(ll)row * NC + col])) * 0.5f;
            st1(&C[(ll)row * NC + col], o);
        }
    }
}

// ---------------- tiled f32 GEMM (fallback tier) ----------------
template <int MODE>
__global__ __launch_bounds__(256) void k_gemm(const float* __restrict__ A, const float* __restrict__ W,
                                              const float* __restrict__ bias, const float* __restrict__ R,
                                              float* __restrict__ C, int M, int K, int Nc) {
    __shared__ float As[64][68];
    __shared__ float Ws[64][68];
    int tid = threadIdx.x;
    int m0 = blockIdx.x * 64, j0 = blockIdx.y * 64;
    int tx = tid & 15, ty = tid >> 4;
    float acc[4][4];
#pragma unroll
    for (int i = 0; i < 4; i++)
#pragma unroll
        for (int j = 0; j < 4; j++) acc[i][j] = 0.f;
    for (int k0 = 0; k0 < K; k0 += 64) {
#pragma unroll
        for (int l = 0; l < 4; l++) {
            int fi = tid + l * 256;
            int m = fi >> 4, kq = fi & 15;
            int row = m0 + m;
            float4 v = make_float4(0.f, 0.f, 0.f, 0.f);
            if (row < M) v = *(const float4*)&A[(ll)row * K + k0 + kq * 4];
            As[kq * 4 + 0][m] = v.x; As[kq * 4 + 1][m] = v.y;
            As[kq * 4 + 2][m] = v.z; As[kq * 4 + 3][m] = v.w;
            float4 w = *(const float4*)&W[(ll)(j0 + m) * K + k0 + kq * 4];
            Ws[kq * 4 + 0][m] = w.x; Ws[kq * 4 + 1][m] = w.y;
            Ws[kq * 4 + 2][m] = w.z; Ws[kq * 4 + 3][m] = w.w;
        }
        __syncthreads();
#pragma unroll
        for (int k = 0; k < 64; k++) {
            float4 av = *(const float4*)&As[k][ty * 4];
            float4 bv = *(const float4*)&Ws[k][tx * 4];
            float a_[4] = {av.x, av.y, av.z, av.w};
            float b_[4] = {bv.x, bv.y, bv.z, bv.w};
#pragma unroll
            for (int i = 0; i < 4; i++)
#pragma unroll
                for (int j = 0; j < 4; j++) acc[i][j] += a_[i] * b_[j];
        }
        __syncthreads();
    }
#pragma unroll
    for (int i = 0; i < 4; i++) {
        int row = m0 + ty * 4 + i;
        if (row >= M) continue;
#pragma unroll
        for (int j = 0; j < 4; j++) {
            int col = j0 + tx * 4 + j;
            float z = acc[i][j] + bias[col];
            float o;
            if (MODE == 0) o = fmaxf(z, 0.f);
            else o = (z + R[(ll)row * Nc + col]) * 0.5f;
            C[(ll)row * Nc + col] = o;
        }
    }
}

// ================= pipeline =================
struct Args {
    const float *x, *ea;
    const int *src, *dstp, *lsrc, *ldst, *eib;
    const float *Wu, *Wv, *We, *w_rel, *b_rel, *w_root, *a, *Wg, *bg, *abias;
    const float *lb1w, *lb1b, *lb2w, *lb2b, *lb3w, *lb3b, *lb4w, *lb4b, *lb5w, *lb5b;
    float *xc, *gouts, *scores;
    int *rowptr, *cnt, *csr, *bsum, *bptr;
    float *xu, *xv;
    float *h;
    char *ws_base;
};

template <typename T1T, typename OT>
static void run_tier(const Args& A, T1T* bufA, T1T* bufB, __half* q0, __half* q1, OT* outw,
                     bool bigLB, hipStream_t stream) {
    constexpr int RPB1 = 256 / (F_ / (16 / (int)sizeof(T1T)));
    const int sg1 = E_ / RPB1;
    const int sg2 = E_ / 32;
    const int efg = (E_ + 15) / 16;
    const int ewg = (int)(((ll)E_ * 64 + 255) / 256);

    k_xuv<<<(N_ + 15) / 16, 256, 0, stream>>>(A.x, A.Wu, A.Wv, A.xu, A.xv);
    k_ef<T1T><<<efg, 256, 0, stream>>>(A.xu, A.xv, A.ea, A.We, A.src, A.dstp, bufA);

#define SEGARGS A.xu, A.xv, A.ea, A.We, A.src, A.dstp, A.rowptr, A.csr, \
                A.xc, A.w_rel, A.b_rel, A.w_root, A.scores, A.eib
    // ---- pass 1: after this, bufB = o_5, bufA = o_6 ----
    k_segv<T1T, OT, true,  false, 0><<<sg1, 256, 0, stream>>>(bufA, bufB, (OT*)nullptr, SEGARGS, 0);
    k_segv<T1T, OT, true,  true,  0><<<sg1, 256, 0, stream>>>(bufB, bufA, (OT*)nullptr, SEGARGS, 0);
    k_pool<T1T><<<B_, 256, 0, stream>>>(A.xc, bufB, A.bptr, A.Wg, A.bg, A.gouts, 0);
    k_segv<T1T, OT, true,  true,  0><<<sg1, 256, 0, stream>>>(bufA, bufB, (OT*)nullptr, SEGARGS, 0);
    k_pool<T1T><<<B_, 256, 0, stream>>>(A.xc, bufA, A.bptr, A.Wg, A.bg, A.gouts, 1);
    k_segv<T1T, OT, true,  true,  0><<<sg1, 256, 0, stream>>>(bufB, bufA, (OT*)nullptr, SEGARGS, 0);
    k_pool<T1T><<<B_, 256, 0, stream>>>(A.xc, bufB, A.bptr, A.Wg, A.bg, A.gouts, 2);
    k_segv<T1T, OT, true,  true,  0><<<sg1, 256, 0, stream>>>(bufA, bufB, (OT*)nullptr, SEGARGS, 0);
    k_pool<T1T><<<B_, 256, 0, stream>>>(A.xc, bufA, A.bptr, A.Wg, A.bg, A.gouts, 3);
    k_segv<T1T, OT, true,  true,  0><<<sg1, 256, 0, stream>>>(bufB, bufA, (OT*)nullptr, SEGARGS, 0);
    k_pool<T1T><<<B_, 256, 0, stream>>>(A.xc, bufB, A.bptr, A.Wg, A.bg, A.gouts, 4);
    k_segv<T1T, OT, false, true,  0><<<sg1, 256, 0, stream>>>(bufA, (T1T*)nullptr, (OT*)nullptr, SEGARGS, 0);
    k_pool<T1T><<<B_, 256, 0, stream>>>(A.xc, bufA, A.bptr, A.Wg, A.bg, A.gouts, 5);

    k_scores<<<B_, 64, 0, stream>>>(A.gouts, A.a, A.abias, A.scores);

    // ---- fold o_5/o_6 into outw; short pass 2 replays only o_1..o_4 ----
    k_comb<T1T, T1T, OT><<<ewg, 256, 0, stream>>>(bufA, bufB, outw, A.scores, A.eib);
    k_ef<__half><<<efg, 256, 0, stream>>>(A.xu, A.xv, A.ea, A.We, A.src, A.dstp, q0);
    k_segv<__half, OT, true,  false, 2><<<sg2, 256, 0, stream>>>(q0, q1, outw, SEGARGS, 0);
    k_segv<__half, OT, true,  false, 2><<<sg2, 256, 0, stream>>>(q1, q0, outw, SEGARGS, 1);
    k_segv<__half, OT, true,  false, 2><<<sg2, 256, 0, stream>>>(q0, q1, outw, SEGARGS, 2);
    k_segv<__half, OT, false, false, 2><<<sg2, 256, 0, stream>>>(q1, (__half*)nullptr, outw, SEGARGS, 3);
#undef SEGARGS

    // ---- h = x + scatter(outw) ----
    k_copy<<<(N_ * 64 + 255) / 256, 256, 0, stream>>>(A.x, A.h, N_ * 64);
    k_scatter<OT><<<ewg, 256, 0, stream>>>(outw, A.dstp, A.h);

    // ---- LinearBlock ----
    if (bigLB) {
        __half* hf  = (__half*)A.ws_base;
        __half* w1h = hf  + (size_t)N_ * 64;
        __half* w2h = w1h + (size_t)SND_ * 64;
        __half* w3h = w2h + (size_t)SND_ * SND_;
        __half* w4h = w3h + (size_t)SND_ * SND_;
        __half* w5h = w4h + (size_t)SND_ * SND_;
        __half* hb1 = w5h + (size_t)64 * SND_;
        __half* hb2 = hb1 + (size_t)N_ * SND_;
        __half* hb3 = hb2 + (size_t)N_ * SND_;
        __half* hb4 = hb3 + (size_t)N_ * SND_;
        k_f2h<<<(N_ * 64 + 255) / 256, 256, 0, stream>>>(A.h, hf, N_ * 64);
        k_f2h<<<(SND_ * 64 + 255) / 256, 256, 0, stream>>>(A.lb1w, w1h, SND_ * 64);
        k_f2h<<<(SND_ * SND_ + 255) / 256, 256, 0, stream>>>(A.lb2w, w2h, SND_ * SND_);
        k_f2h<<<(SND_ * SND_ + 255) / 256, 256, 0, stream>>>(A.lb3w, w3h, SND_ * SND_);
        k_f2h<<<(SND_ * SND_ + 255) / 256, 256, 0, stream>>>(A.lb4w, w4h, SND_ * SND_);
        k_f2h<<<(SND_ * 64 + 255) / 256, 256, 0, stream>>>(A.lb5w, w5h, 64 * SND_);
        int gb = (N_ + 63) / 64;
        k_gemm_w<24, 0, __half><<<gb, 256, 0, stream>>>(hf,  w1h, A.lb1b, nullptr, hb1, N_, 64);
        k_gemm_w<24, 0, __half><<<gb, 256, 0, stream>>>(hb1, w2h, A.lb2b, nullptr, hb2, N_, SND_);
        k_gemm_w<24, 1, __half><<<gb, 256, 0, stream>>>(hb2, w3h, A.lb3b, hb1,    hb3, N_, SND_);
        k_gemm_w<24, 1, __half><<<gb, 256, 0, stream>>>(hb3, w4h, A.lb4b, hb3,    hb4, N_, SND_);
        k_gemm_w<4,  0, float ><<<gb, 256, 0, stream>>>(hb4, w5h, A.lb5b, nullptr, A.h, N_, SND_);
    } else {
        const int CH = 12800;
        size_t cb = (size_t)CH * SND_ * 4;
        float* b1 = (float*)A.ws_base;
        float* b2 = (float*)(A.ws_base + cb);
        float* b3 = (float*)(A.ws_base + 2 * cb);
        for (int r0 = 0; r0 < N_; r0 += CH) {
            int m = (N_ - r0 < CH) ? (N_ - r0) : CH;
            dim3 g6((m + 63) / 64, SND_ / 64);
            dim3 g1((m + 63) / 64, 1);
            k_gemm<0><<<g6, 256, 0, stream>>>(A.h + (ll)r0 * 64, A.lb1w, A.lb1b, nullptr, b1, m, 64,   SND_);
            k_gemm<0><<<g6, 256, 0, stream>>>(b1, A.lb2w, A.lb2b, nullptr, b2, m, SND_, SND_);
            k_gemm<1><<<g6, 256, 0, stream>>>(b2, A.lb3w, A.lb3b, b1,      b3, m, SND_, SND_);
            k_gemm<1><<<g6, 256, 0, stream>>>(b3, A.lb4w, A.lb4b, b3,      b1, m, SND_, SND_);
            k_gemm<0><<<g1, 256, 0, stream>>>(b1, A.lb5w, A.lb5b, nullptr, A.h + (ll)r0 * 64, m, SND_, 64);
        }
    }
}

extern "C" void kernel_launch(void* const* d_in, const int* in_sizes, int n_in,
                              void* d_out, int out_size, void* d_ws, size_t ws_size,
                              hipStream_t stream) {
    (void)in_sizes; (void)n_in; (void)out_size;
    Args A;
    A.x      = (const float*)d_in[0];
    A.ea     = (const float*)d_in[1];
    const int* eidx = (const int*)d_in[2];
    const int* lgp  = (const int*)d_in[3];
    A.eib    = (const int*)d_in[4];
    A.Wu     = (const float*)d_in[5];
    A.Wv     = (const float*)d_in[6];
    A.We     = (const float*)d_in[7];
    A.w_rel  = (const float*)d_in[8];
    A.b_rel  = (const float*)d_in[9];
    A.w_root = (const float*)d_in[10];
    A.a      = (const float*)d_in[11];
    A.Wg     = (const float*)d_in[12];
    A.bg     = (const float*)d_in[13];
    A.abias  = (const float*)d_in[14];
    A.lb1w = (const float*)d_in[15]; A.lb1b = (const float*)d_in[16];
    A.lb2w = (const float*)d_in[17]; A.lb2b = (const float*)d_in[18];
    A.lb3w = (const float*)d_in[19]; A.lb3b = (const float*)d_in[20];
    A.lb4w = (const float*)d_in[21]; A.lb4b = (const float*)d_in[22];
    A.lb5w = (const float*)d_in[23]; A.lb5b = (const float*)d_in[24];
    A.src  = eidx;
    A.dstp = eidx + E_;
    A.lsrc = lgp;
    A.ldst = lgp + ELG_;
    A.h       = (float*)d_out;
    A.ws_base = (char*)d_ws;

    char* p = (char*)d_ws;
    auto alloc = [&](size_t bytes) -> char* {
        char* r = p;
        p += (bytes + 255) & ~(size_t)255;
        return r;
    };
    A.xc     = (float*)alloc((size_t)E_ * 4);
    A.gouts  = (float*)alloc((size_t)B_ * T_ * 64 * 4);
    A.scores = (float*)alloc((size_t)B_ * T_ * 4);
    A.rowptr = (int*)alloc((size_t)(E_ + 1) * 4);
    A.cnt    = (int*)alloc((size_t)E_ * 4);
    A.csr    = (int*)alloc((size_t)ELG_ * 4);
    A.bsum   = (int*)alloc(8192);
    A.bptr   = (int*)alloc((size_t)(B_ + 1) * 4);
    A.xu     = (float*)alloc((size_t)N_ * 64 * 4);
    A.xv     = (float*)alloc((size_t)N_ * 64 * 4);

    const size_t NEED_T1 = 244736768ull;
    const size_t NEED_T3 = 193536768ull;

    if (ws_size < NEED_T3) {
        k_zero<<<(N_ * 64 + 255) / 256, 256, 0, stream>>>((float*)d_out, N_ * 64);
        return;
    }

    hipMemsetAsync(A.cnt, 0, (size_t)E_ * 4, stream);
    k_count<<<(ELG_ + 255) / 256, 256, 0, stream>>>(A.ldst, A.cnt);
    int nb1 = (E_ + 255) / 256;
    k_scan1<<<nb1, 256, 0, stream>>>(A.cnt, A.rowptr, A.bsum);
    k_scan2<<<1, 256, 0, stream>>>(A.bsum, nb1);
    k_scan3<<<nb1, 256, 0, stream>>>(A.rowptr, A.bsum);
    hipMemsetAsync(A.cnt, 0, (size_t)E_ * 4, stream);
    k_fill<<<(ELG_ + 255) / 256, 256, 0, stream>>>(A.lsrc, A.ldst, A.rowptr, A.cnt, A.csr);
    k_bptr<<<(B_ + 1 + 255) / 256, 256, 0, stream>>>(A.eib, A.bptr);

    if (ws_size >= NEED_T1) {
        float* bufA = (float*)alloc((size_t)E_ * 64 * 4);
        float* bufB = (float*)alloc((size_t)E_ * 64 * 4);
        __half* q0 = (__half*)bufA;
        __half* q1 = q0 + (size_t)E_ * 64;
        run_tier<float, float>(A, bufA, bufB, q0, q1, (float*)bufB, true, stream);
    } else {
        __half* bufA = (__half*)alloc((size_t)E_ * 64 * 2);
        __half* bufB = (__half*)alloc((size_t)E_ * 64 * 2);
        __half* outw = (__half*)alloc((size_t)E_ * 64 * 2);
        run_tier<__half, __half>(A, bufA, bufB, bufA, bufB, outw, false, stream);
    }
}

// Round 14
// 2029.227 us; speedup vs baseline: 1.0966x; 1.0966x over previous
//
#include <hip/hip_runtime.h>
#include <hip/hip_fp16.h>

#define N_   50000
#define E_   400000
#define ELG_ 1600000
#define B_   2000
#define F_   64
#define ED_  16
#define T_   6
#define SND_ 384

typedef long long ll;
typedef _Float16 f16x8 __attribute__((ext_vector_type(8)));
typedef float f32x4 __attribute__((ext_vector_type(4)));
typedef float fv4 __attribute__((ext_vector_type(4)));

__device__ inline float ldc(const float* p, ll i) { return p[i]; }
__device__ inline float ldc(const __half* p, ll i) { return __half2float(p[i]); }
__device__ inline void st1(float* p, float v) { *p = v; }
__device__ inline void st1(__half* p, float v) { *p = __float2half(v); }

template <int FPL>
__device__ inline void ldN(const float* p, float (&o)[FPL]) {
#pragma unroll
    for (int c = 0; c < FPL; c += 4) {
        fv4 v = *(const fv4*)(p + c);
        o[c] = v.x; o[c + 1] = v.y; o[c + 2] = v.z; o[c + 3] = v.w;
    }
}
template <int FPL>
__device__ inline void ldN(const __half* p, float (&o)[FPL]) {
#pragma unroll
    for (int c = 0; c < FPL; c += 8) {
        f16x8 raw = *(const f16x8*)(p + c);
#pragma unroll
        for (int i = 0; i < 8; i++) o[c + i] = (float)raw[i];
    }
}
template <int FPL>
__device__ inline void stN(float* p, const float (&v)[FPL]) {
#pragma unroll
    for (int c = 0; c < FPL; c += 4) {
        fv4 t; t.x = v[c]; t.y = v[c + 1]; t.z = v[c + 2]; t.w = v[c + 3];
        *(fv4*)(p + c) = t;
    }
}
template <int FPL>
__device__ inline void stN(__half* p, const float (&v)[FPL]) {
#pragma unroll
    for (int c = 0; c < FPL; c += 8) {
        f16x8 t;
#pragma unroll
        for (int i = 0; i < 8; i++) t[i] = (_Float16)v[c + i];
        *(f16x8*)(p + c) = t;
    }
}

// ---------------- CSR build ----------------
__global__ __launch_bounds__(256) void k_count(const int* __restrict__ ldst, int* __restrict__ cnt) {
    int i = blockIdx.x * 256 + threadIdx.x;
    if (i < ELG_) atomicAdd(&cnt[ldst[i]], 1);
}

__global__ __launch_bounds__(256) void k_scan1(const int* __restrict__ cnt, int* __restrict__ rowptr,
                                               int* __restrict__ bsum) {
    __shared__ int s[256];
    int tid = threadIdx.x;
    int i = blockIdx.x * 256 + tid;
    int v = (i < E_) ? cnt[i] : 0;
    s[tid] = v;
    __syncthreads();
    for (int off = 1; off < 256; off <<= 1) {
        int t = (tid >= off) ? s[tid - off] : 0;
        __syncthreads();
        s[tid] += t;
        __syncthreads();
    }
    if (i < E_) rowptr[i] = s[tid] - v;
    if (tid == 255) bsum[blockIdx.x] = s[255];
}

__global__ __launch_bounds__(256) void k_scan2(int* __restrict__ bsum, int nb) {
    __shared__ int s[256];
    __shared__ int carry_s;
    int tid = threadIdx.x;
    if (tid == 0) carry_s = 0;
    __syncthreads();
    for (int base = 0; base < nb; base += 256) {
        int i = base + tid;
        int v = (i < nb) ? bsum[i] : 0;
        s[tid] = v;
        __syncthreads();
        for (int off = 1; off < 256; off <<= 1) {
            int t = (tid >= off) ? s[tid - off] : 0;
            __syncthreads();
            s[tid] += t;
            __syncthreads();
        }
        int c = carry_s;
        if (i < nb) bsum[i] = s[tid] - v + c;
        __syncthreads();
        if (tid == 0) carry_s = c + s[255];
        __syncthreads();
    }
}

__global__ __launch_bounds__(256) void k_scan3(int* __restrict__ rowptr, const int* __restrict__ bsum) {
    int i = blockIdx.x * 256 + threadIdx.x;
    if (i < E_) rowptr[i] += bsum[i >> 8];
    if (i == 0) rowptr[E_] = ELG_;
}

__global__ __launch_bounds__(256) void k_fill(const int* __restrict__ lsrc, const int* __restrict__ ldst,
                                              const int* __restrict__ rowptr, int* __restrict__ cursor,
                                              int* __restrict__ csr) {
    int i = blockIdx.x * 256 + threadIdx.x;
    if (i < ELG_) {
        int d = ldst[i];
        int pos = atomicAdd(&cursor[d], 1);
        csr[rowptr[d] + pos] = lsrc[i];
    }
}

__global__ __launch_bounds__(256) void k_bptr(const int* __restrict__ eib, int* __restrict__ bptr) {
    int b = blockIdx.x * 256 + threadIdx.x;
    if (b > B_) return;
    int lo = 0, hi = E_;
    while (lo < hi) {
        int mid = (lo + hi) >> 1;
        if (eib[mid] < b) lo = mid + 1; else hi = mid;
    }
    bptr[b] = lo;
}

// ---------------- node projections ----------------
__global__ __launch_bounds__(256) void k_xuv(const float* __restrict__ x,
                                             const float* __restrict__ Wu, const float* __restrict__ Wv,
                                             float* __restrict__ xu, float* __restrict__ xv) {
    __shared__ float wus[64 * 65];
    __shared__ float wvs[64 * 65];
    __shared__ float xs[16][64];
    int tid = threadIdx.x;
    for (int i = tid; i < 4096; i += 256) {
        int f = i >> 6, k = i & 63;
        wus[k * 65 + f] = Wu[i];
        wvs[k * 65 + f] = Wv[i];
    }
    int r0 = blockIdx.x * 16;
    for (int i = tid; i < 16 * 64; i += 256) {
        int r = i >> 6, j = i & 63;
        int row = r0 + r;
        xs[r][j] = (row < N_) ? x[(ll)row * 64 + j] : 0.f;
    }
    __syncthreads();
    int j = tid & 63, lr0 = tid >> 6;
    float su[4] = {0, 0, 0, 0}, sv[4] = {0, 0, 0, 0};
    for (int k = 0; k < 64; k++) {
        float wu = wus[k * 65 + j];
        float wv = wvs[k * 65 + j];
#pragma unroll
        for (int r = 0; r < 4; r++) {
            float xr = xs[lr0 + r * 4][k];
            su[r] += xr * wu;
            sv[r] += xr * wv;
        }
    }
#pragma unroll
    for (int r = 0; r < 4; r++) {
        int row = r0 + lr0 + r * 4;
        if (row < N_) {
            xu[(ll)row * 64 + j] = su[r];
            xv[(ll)row * 64 + j] = sv[r];
        }
    }
}

// ---------------- edge features -> state buffer (o_0 = ef) ----------------
template <typename ET>
__global__ __launch_bounds__(256) void k_ef(const float* __restrict__ xu, const float* __restrict__ xv,
                                            const float* __restrict__ ea, const float* __restrict__ We,
                                            const int* __restrict__ src, const int* __restrict__ dst,
                                            ET* __restrict__ ef) {
    __shared__ float wes[16 * 65];
    int tid = threadIdx.x;
    for (int i = tid; i < 1024; i += 256) {
        wes[(i & 15) * 65 + (i >> 4)] = We[i];
    }
    __syncthreads();
    int wid = tid >> 6, f = tid & 63;
    ll e0 = (ll)blockIdx.x * 16;
#pragma unroll
    for (int r = 0; r < 4; r++) {
        ll e = e0 + wid + r * 4;
        if (e >= E_) return;
        int s = src[e], d = dst[e];
        float v = xu[(ll)s * 64 + f] + xv[(ll)d * 64 + f];
#pragma unroll
        for (int k = 0; k < 16; k++) v += ea[e * 16 + k] * wes[k * 65 + f];
        st1(&ef[e * 64 + f], v * (1.0f / 3.0f));
    }
}

// ------ vectorized fused seg step; 4-way unrolled dual-accumulator gather ------
// WOUT: write o to nxt.  WXC: GraphConv logit xc.  ACC: 1 = outw = w*o, 2 = outw += w*o.
template <typename T, typename OT, bool WOUT, bool WXC, int ACC>
__global__ __launch_bounds__(256) void k_segv(
    const T* __restrict__ state, T* __restrict__ nxt, OT* __restrict__ outw,
    const float* __restrict__ xu, const float* __restrict__ xv,
    const float* __restrict__ ea, const float* __restrict__ We,
    const int* __restrict__ esrc, const int* __restrict__ edst,
    const int* __restrict__ rowptr, const int* __restrict__ csr,
    float* __restrict__ xc, const float* __restrict__ w_rel,
    const float* __restrict__ b_rel, const float* __restrict__ w_root,
    const float* __restrict__ scores, const int* __restrict__ eib, int tslot)
{
    constexpr int FPL = 16 / sizeof(T);
    constexpr int LPR = F_ / FPL;
    constexpr int RPB = 256 / LPR;
    constexpr bool EF = WOUT || (ACC > 0);
    __shared__ float wes[16 * 65];
    int tid = threadIdx.x;
    if (EF) {
        for (int i = tid; i < 1024; i += 256)
            wes[(i & 15) * 65 + (i >> 4)] = We[i];
        __syncthreads();
    }
    int sub = tid % LPR;
    int r   = tid / LPR;
    ll d = (ll)blockIdx.x * RPB + r;
    int f0 = sub * FPL;
    int p0 = rowptr[d], p1 = rowptr[d + 1];
    float acc[FPL], acc2[FPL];
#pragma unroll
    for (int j = 0; j < FPL; j++) { acc[j] = 0.f; acc2[j] = 0.f; }
    int p = p0;
    for (; p + 4 <= p1; p += 4) {
        int s0 = csr[p], s1 = csr[p + 1], s2 = csr[p + 2], s3 = csr[p + 3];
        float v0[FPL], v1[FPL], v2[FPL], v3[FPL];
        ldN<FPL>(&state[(ll)s0 * F_ + f0], v0);
        ldN<FPL>(&state[(ll)s1 * F_ + f0], v1);
        ldN<FPL>(&state[(ll)s2 * F_ + f0], v2);
        ldN<FPL>(&state[(ll)s3 * F_ + f0], v3);
#pragma unroll
        for (int j = 0; j < FPL; j++) { acc[j] += v0[j] + v2[j]; acc2[j] += v1[j] + v3[j]; }
    }
    for (; p + 2 <= p1; p += 2) {
        int s0 = csr[p], s1 = csr[p + 1];
        float v0[FPL], v1[FPL];
        ldN<FPL>(&state[(ll)s0 * F_ + f0], v0);
        ldN<FPL>(&state[(ll)s1 * F_ + f0], v1);
#pragma unroll
        for (int j = 0; j < FPL; j++) { acc[j] += v0[j]; acc2[j] += v1[j]; }
    }
    if (p < p1) {
        int s0 = csr[p];
        float v0[FPL];
        ldN<FPL>(&state[(ll)s0 * F_ + f0], v0);
#pragma unroll
        for (int j = 0; j < FPL; j++) acc[j] += v0[j];
    }
#pragma unroll
    for (int j = 0; j < FPL; j++) acc[j] += acc2[j];
    if (EF) {
        int se = esrc[d], de = edst[d];
        float o[FPL], xuv[FPL], xvv[FPL];
        ldN<FPL>(&xu[(ll)se * 64 + f0], xuv);
        ldN<FPL>(&xv[(ll)de * 64 + f0], xvv);
#pragma unroll
        for (int j = 0; j < FPL; j++) o[j] = xuv[j] + xvv[j];
#pragma unroll
        for (int k = 0; k < 16; k++) {
            float eav = ea[d * 16 + k];
#pragma unroll
            for (int j = 0; j < FPL; j++) o[j] += eav * wes[k * 65 + f0 + j];
        }
#pragma unroll
        for (int j = 0; j < FPL; j++) o[j] = o[j] * (1.0f / 3.0f) + acc[j];
        if (WOUT) stN<FPL>(&nxt[(ll)d * F_ + f0], o);
        if (ACC > 0) {
            float w = scores[eib[d] * 6 + tslot];
            float ow[FPL];
            if (ACC == 2) ldN<FPL>(&outw[(ll)d * F_ + f0], ow);
            else {
#pragma unroll
                for (int j = 0; j < FPL; j++) ow[j] = 0.f;
            }
#pragma unroll
            for (int j = 0; j < FPL; j++) ow[j] += w * o[j];
            stN<FPL>(&outw[(ll)d * F_ + f0], ow);
        }
    }
    if (WXC) {
        float ov[FPL];
        ldN<FPL>(&state[(ll)d * F_ + f0], ov);
        float part = 0.f;
#pragma unroll
        for (int j = 0; j < FPL; j++)
            part += acc[j] * w_rel[f0 + j] + ov[j] * w_root[f0 + j];
#pragma unroll
        for (int off = LPR / 2; off; off >>= 1) part += __shfl_xor(part, off, 64);
        if (sub == 0) xc[d] = part + b_rel[0];
    }
}

// ---------------- fold o_5,o_6 into outw (fallback tier only) ----------------
template <typename TA, typename TB, typename OT>
__global__ __launch_bounds__(256) void k_comb(const TA* __restrict__ o6, const TB* __restrict__ o5,
                                              OT* __restrict__ outw, const float* __restrict__ scores,
                                              const int* __restrict__ eib) {
    ll i = (ll)blockIdx.x * 256 + threadIdx.x;
    if (i >= (ll)E_ * 64) return;
    int e = (int)(i >> 6);
    int b = eib[e];
    float v = scores[b * 6 + 4] * ldc(o5, i) + scores[b * 6 + 5] * ldc(o6, i);
    st1(&outw[i], v);
}

// ---------------- scatter s4*o5+s5*o6 into h (coalesced 64-lane rows) ----------------
template <typename TA>
__global__ __launch_bounds__(256) void k_scat2(const TA* __restrict__ o6, const TA* __restrict__ o5,
                                               const float* __restrict__ scores, const int* __restrict__ eib,
                                               const int* __restrict__ dst, float* __restrict__ h) {
    ll i = (ll)blockIdx.x * 256 + threadIdx.x;
    if (i >= (ll)E_ * 64) return;
    int e = (int)(i >> 6), f = (int)(i & 63);
    int b = eib[e];
    float v = scores[b * 6 + 4] * ldc(o5, i) + scores[b * 6 + 5] * ldc(o6, i);
    atomicAdd(&h[(ll)dst[e] * 64 + f], v);
}

// ---------------- scatter s0*o1+s1*o2+s2*o3+s3*o4 into h ----------------
__global__ __launch_bounds__(256) void k_scat4(const __half* __restrict__ o1, const __half* __restrict__ o2,
                                               const __half* __restrict__ o3, const __half* __restrict__ o4,
                                               const float* __restrict__ scores, const int* __restrict__ eib,
                                               const int* __restrict__ dst, float* __restrict__ h) {
    ll i = (ll)blockIdx.x * 256 + threadIdx.x;
    if (i >= (ll)E_ * 64) return;
    int e = (int)(i >> 6), f = (int)(i & 63);
    const float* sc = &scores[eib[e] * 6];
    float v = sc[0] * ldc(o1, i) + sc[1] * ldc(o2, i) + sc[2] * ldc(o3, i) + sc[3] * ldc(o4, i);
    atomicAdd(&h[(ll)dst[e] * 64 + f], v);
}

// ---------------- per-batch softmax + attention pool + tanh(g@Wg^T+bg) ----------------
template <typename ST>
__global__ __launch_bounds__(256) void k_pool(const float* __restrict__ xc, const ST* __restrict__ out_t,
                                              const int* __restrict__ bptr, const float* __restrict__ Wg,
                                              const float* __restrict__ bg, float* __restrict__ gouts,
                                              int tslot) {
    int b = blockIdx.x;
    int tid = threadIdx.x;
    int p0 = bptr[b], p1 = bptr[b + 1];
    __shared__ float red[256];
    __shared__ float gsh[64];
    float m = -1e30f;
    for (int i = p0 + tid; i < p1; i += 256) m = fmaxf(m, xc[i]);
    red[tid] = m;
    __syncthreads();
    for (int o = 128; o; o >>= 1) { if (tid < o) red[tid] = fmaxf(red[tid], red[tid + o]); __syncthreads(); }
    m = red[0];
    __syncthreads();
    float ss = 0.f;
    for (int i = p0 + tid; i < p1; i += 256) ss += __expf(xc[i] - m);
    red[tid] = ss;
    __syncthreads();
    for (int o = 128; o; o >>= 1) { if (tid < o) red[tid] += red[tid + o]; __syncthreads(); }
    float inv = 1.0f / (red[0] + 1e-16f);
    __syncthreads();
    int lane = tid & 63, grp = tid >> 6;
    float acc = 0.f;
    for (int e = p0 + grp; e < p1; e += 4) {
        float w = __expf(xc[e] - m) * inv;
        acc += ldc(out_t, (ll)e * 64 + lane) * w;
    }
    red[tid] = acc;
    __syncthreads();
    if (tid < 64) gsh[tid] = red[tid] + red[tid + 64] + red[tid + 128] + red[tid + 192];
    __syncthreads();
    if (tid < 64) {
        float z = bg[tid];
#pragma unroll 8
        for (int k = 0; k < 64; k++) z += gsh[k] * Wg[tid * 64 + k];
        gouts[((ll)b * T_ + tslot) * 64 + tid] = tanhf(z);
    }
}

// ---------------- per-batch scores over T ----------------
__global__ __launch_bounds__(64) void k_scores(const float* __restrict__ gouts, const float* __restrict__ a,
                                               const float* __restrict__ ab, float* __restrict__ scores) {
    int b = blockIdx.x, f = threadIdx.x;
    float lg[6];
#pragma unroll
    for (int t = 0; t < 6; t++) {
        float v = gouts[((ll)b * T_ + t) * 64 + f] * a[f * 6 + t];
#pragma unroll
        for (int o = 32; o; o >>= 1) v += __shfl_xor(v, o, 64);
        lg[t] = v + ab[t];
    }
    float m = lg[0];
#pragma unroll
    for (int t = 1; t < 6; t++) m = fmaxf(m, lg[t]);
    float s = 0.f;
#pragma unroll
    for (int t = 0; t < 6; t++) { lg[t] = __expf(lg[t] - m); s += lg[t]; }
    if (f == 0) {
        float inv = 1.0f / s;
#pragma unroll
        for (int t = 0; t < 6; t++) scores[b * 6 + t] = lg[t] * inv;
    }
}

__global__ __launch_bounds__(256) void k_copy(const float* __restrict__ in, float* __restrict__ out, int n) {
    int i = blockIdx.x * 256 + threadIdx.x;
    if (i < n) out[i] = in[i];
}

__global__ __launch_bounds__(256) void k_zero(float* __restrict__ out, int n) {
    int i = blockIdx.x * 256 + threadIdx.x;
    if (i < n) out[i] = 0.f;
}

__global__ __launch_bounds__(256) void k_f2h(const float* __restrict__ in, __half* __restrict__ out, int n) {
    int i = blockIdx.x * 256 + threadIdx.x;
    if (i < n) out[i] = __float2half(in[i]);
}

// ---------------- final scatter from outw (fallback tier) ----------------
template <typename OT>
__global__ __launch_bounds__(256) void k_scatter(const OT* __restrict__ outw, const int* __restrict__ dst,
                                                 float* __restrict__ h) {
    ll i = (ll)blockIdx.x * 256 + threadIdx.x;
    if (i >= (ll)E_ * 64) return;
    int e = (int)(i >> 6), f = (int)(i & 63);
    atomicAdd(&h[(ll)dst[e] * 64 + f], ldc(outw, i));
}

// ---------------- MFMA f16 GEMM, 64x64 tile (round-9 proven) ----------------
template <int MODE, typename CT>  // MODE 0: relu(z)  1: (z + R)/2
__global__ __launch_bounds__(256) void k_gemm_h(
    const __half* __restrict__ Ah, const __half* __restrict__ Wh,
    const float* __restrict__ bias, const __half* __restrict__ R,
    CT* __restrict__ C, int M, int K, int Nc)
{
    __shared__ _Float16 As[64][40];
    __shared__ _Float16 Ws[64][40];
    int tid = threadIdx.x;
    int m0 = blockIdx.x * 64, j0 = blockIdx.y * 64;
    int wv = tid >> 6, lane = tid & 63;
    int srow = tid >> 2, skq = tid & 3;
    f32x4 acc[4] = {};
    const int arow = m0 + srow;
    for (int k0 = 0; k0 < K; k0 += 32) {
        f16x8 a8 = {};
        if (arow < M) a8 = *(const f16x8*)&Ah[(ll)arow * K + k0 + skq * 8];
        *(f16x8*)&As[srow][skq * 8] = a8;
        f16x8 w8 = *(const f16x8*)&Wh[(ll)(j0 + srow) * K + k0 + skq * 8];
        *(f16x8*)&Ws[srow][skq * 8] = w8;
        __syncthreads();
        f16x8 af = *(const f16x8*)&As[wv * 16 + (lane & 15)][(lane >> 4) * 8];
#pragma unroll
        for (int nt = 0; nt < 4; nt++) {
            f16x8 bf = *(const f16x8*)&Ws[nt * 16 + (lane & 15)][(lane >> 4) * 8];
            acc[nt] = __builtin_amdgcn_mfma_f32_16x16x32_f16(af, bf, acc[nt], 0, 0, 0);
        }
        __syncthreads();
    }
    int colb = lane & 15;
    int row0 = m0 + wv * 16 + (lane >> 4) * 4;
#pragma unroll
    for (int nt = 0; nt < 4; nt++) {
        int col = j0 + nt * 16 + colb;
#pragma unroll
        for (int rg = 0; rg < 4; rg++) {
            int row = row0 + rg;
            if (row >= M) continue;
            float z = acc[nt][rg] + bias[col];
            float o;
            if (MODE == 0) o = fmaxf(z, 0.f);
            else o = (z + __half2float(R[(ll)row * Nc + col])) * 0.5f;
            st1(&C[(ll)row * Nc + col], o);
        }
    }
}

// ---------------- tiled f32 GEMM (fallback tier) ----------------
template <int MODE>
__global__ __launch_bounds__(256) void k_gemm(const float* __restrict__ A, const float* __restrict__ W,
                                              const float* __restrict__ bias, const float* __restrict__ R,
                                              float* __restrict__ C, int M, int K, int Nc) {
    __shared__ float As[64][68];
    __shared__ float Ws[64][68];
    int tid = threadIdx.x;
    int m0 = blockIdx.x * 64, j0 = blockIdx.y * 64;
    int tx = tid & 15, ty = tid >> 4;
    float acc[4][4];
#pragma unroll
    for (int i = 0; i < 4; i++)
#pragma unroll
        for (int j = 0; j < 4; j++) acc[i][j] = 0.f;
    for (int k0 = 0; k0 < K; k0 += 64) {
#pragma unroll
        for (int l = 0; l < 4; l++) {
            int fi = tid + l * 256;
            int m = fi >> 4, kq = fi & 15;
            int row = m0 + m;
            float4 v = make_float4(0.f, 0.f, 0.f, 0.f);
            if (row < M) v = *(const float4*)&A[(ll)row * K + k0 + kq * 4];
            As[kq * 4 + 0][m] = v.x; As[kq * 4 + 1][m] = v.y;
            As[kq * 4 + 2][m] = v.z; As[kq * 4 + 3][m] = v.w;
            float4 w = *(const float4*)&W[(ll)(j0 + m) * K + k0 + kq * 4];
            Ws[kq * 4 + 0][m] = w.x; Ws[kq * 4 + 1][m] = w.y;
            Ws[kq * 4 + 2][m] = w.z; Ws[kq * 4 + 3][m] = w.w;
        }
        __syncthreads();
#pragma unroll
        for (int k = 0; k < 64; k++) {
            float4 av = *(const float4*)&As[k][ty * 4];
            float4 bv = *(const float4*)&Ws[k][tx * 4];
            float a_[4] = {av.x, av.y, av.z, av.w};
            float b_[4] = {bv.x, bv.y, bv.z, bv.w};
#pragma unroll
            for (int i = 0; i < 4; i++)
#pragma unroll
                for (int j = 0; j < 4; j++) acc[i][j] += a_[i] * b_[j];
        }
        __syncthreads();
    }
#pragma unroll
    for (int i = 0; i < 4; i++) {
        int row = m0 + ty * 4 + i;
        if (row >= M) continue;
#pragma unroll
        for (int j = 0; j < 4; j++) {
            int col = j0 + tx * 4 + j;
            float z = acc[i][j] + bias[col];
            float o;
            if (MODE == 0) o = fmaxf(z, 0.f);
            else o = (z + R[(ll)row * Nc + col]) * 0.5f;
            C[(ll)row * Nc + col] = o;
        }
    }
}

// ================= pipeline =================
struct Args {
    const float *x, *ea;
    const int *src, *dstp, *lsrc, *ldst, *eib;
    const float *Wu, *Wv, *We, *w_rel, *b_rel, *w_root, *a, *Wg, *bg, *abias;
    const float *lb1w, *lb1b, *lb2w, *lb2b, *lb3w, *lb3b, *lb4w, *lb4b, *lb5w, *lb5b;
    float *xc, *gouts, *scores;
    int *rowptr, *cnt, *csr, *bsum, *bptr;
    float *xu, *xv;
    float *h;
    char *ws_base;
};

template <typename T1T, typename OT>
static void run_tier(const Args& A, T1T* bufA, T1T* bufB,
                     __half* q0, __half* q1, __half* q2, __half* q3,  // q2/q3 null => fallback path
                     OT* outw, bool bigLB, hipStream_t stream) {
    constexpr int RPB1 = 256 / (F_ / (16 / (int)sizeof(T1T)));
    const int sg1 = E_ / RPB1;
    const int sg2 = E_ / 32;
    const int efg = (E_ + 15) / 16;
    const int ewg = (int)(((ll)E_ * 64 + 255) / 256);

    k_xuv<<<(N_ + 15) / 16, 256, 0, stream>>>(A.x, A.Wu, A.Wv, A.xu, A.xv);
    k_ef<T1T><<<efg, 256, 0, stream>>>(A.xu, A.xv, A.ea, A.We, A.src, A.dstp, bufA);

#define SEGARGS A.xu, A.xv, A.ea, A.We, A.src, A.dstp, A.rowptr, A.csr, \
                A.xc, A.w_rel, A.b_rel, A.w_root, A.scores, A.eib
    // ---- pass 1: after this, bufB = o_5, bufA = o_6 ----
    k_segv<T1T, OT, true,  false, 0><<<sg1, 256, 0, stream>>>(bufA, bufB, (OT*)nullptr, SEGARGS, 0);
    k_segv<T1T, OT, true,  true,  0><<<sg1, 256, 0, stream>>>(bufB, bufA, (OT*)nullptr, SEGARGS, 0);
    k_pool<T1T><<<B_, 256, 0, stream>>>(A.xc, bufB, A.bptr, A.Wg, A.bg, A.gouts, 0);
    k_segv<T1T, OT, true,  true,  0><<<sg1, 256, 0, stream>>>(bufA, bufB, (OT*)nullptr, SEGARGS, 0);
    k_pool<T1T><<<B_, 256, 0, stream>>>(A.xc, bufA, A.bptr, A.Wg, A.bg, A.gouts, 1);
    k_segv<T1T, OT, true,  true,  0><<<sg1, 256, 0, stream>>>(bufB, bufA, (OT*)nullptr, SEGARGS, 0);
    k_pool<T1T><<<B_, 256, 0, stream>>>(A.xc, bufB, A.bptr, A.Wg, A.bg, A.gouts, 2);
    k_segv<T1T, OT, true,  true,  0><<<sg1, 256, 0, stream>>>(bufA, bufB, (OT*)nullptr, SEGARGS, 0);
    k_pool<T1T><<<B_, 256, 0, stream>>>(A.xc, bufA, A.bptr, A.Wg, A.bg, A.gouts, 3);
    k_segv<T1T, OT, true,  true,  0><<<sg1, 256, 0, stream>>>(bufB, bufA, (OT*)nullptr, SEGARGS, 0);
    k_pool<T1T><<<B_, 256, 0, stream>>>(A.xc, bufB, A.bptr, A.Wg, A.bg, A.gouts, 4);
    k_segv<T1T, OT, false, true,  0><<<sg1, 256, 0, stream>>>(bufA, (T1T*)nullptr, (OT*)nullptr, SEGARGS, 0);
    k_pool<T1T><<<B_, 256, 0, stream>>>(A.xc, bufA, A.bptr, A.Wg, A.bg, A.gouts, 5);

    k_scores<<<B_, 64, 0, stream>>>(A.gouts, A.a, A.abias, A.scores);

    k_copy<<<(N_ * 64 + 255) / 256, 256, 0, stream>>>(A.x, A.h, N_ * 64);

    if (q2) {
        // ---- T1 path: scatter o5/o6 now (still f32 in bufB/bufA), then 4 pure f16 replays ----
        k_scat2<T1T><<<ewg, 256, 0, stream>>>(bufA, bufB, A.scores, A.eib, A.dstp, A.h);
        k_ef<__half><<<efg, 256, 0, stream>>>(A.xu, A.xv, A.ea, A.We, A.src, A.dstp, q0);  // o0
        k_segv<__half, OT, true, false, 0><<<sg2, 256, 0, stream>>>(q0, q1, (OT*)nullptr, SEGARGS, 0);  // o1
        k_segv<__half, OT, true, false, 0><<<sg2, 256, 0, stream>>>(q1, q2, (OT*)nullptr, SEGARGS, 0);  // o2
        k_segv<__half, OT, true, false, 0><<<sg2, 256, 0, stream>>>(q2, q3, (OT*)nullptr, SEGARGS, 0);  // o3
        k_segv<__half, OT, true, false, 0><<<sg2, 256, 0, stream>>>(q3, q0, (OT*)nullptr, SEGARGS, 0);  // o4 -> q0
        k_scat4<<<ewg, 256, 0, stream>>>(q1, q2, q3, q0, A.scores, A.eib, A.dstp, A.h);
    } else {
        // ---- fallback: outw accumulation path ----
        k_comb<T1T, T1T, OT><<<ewg, 256, 0, stream>>>(bufA, bufB, outw, A.scores, A.eib);
        k_ef<__half><<<efg, 256, 0, stream>>>(A.xu, A.xv, A.ea, A.We, A.src, A.dstp, q0);
        k_segv<__half, OT, true,  false, 2><<<sg2, 256, 0, stream>>>(q0, q1, outw, SEGARGS, 0);
        k_segv<__half, OT, true,  false, 2><<<sg2, 256, 0, stream>>>(q1, q0, outw, SEGARGS, 1);
        k_segv<__half, OT, true,  false, 2><<<sg2, 256, 0, stream>>>(q0, q1, outw, SEGARGS, 2);
        k_segv<__half, OT, false, false, 2><<<sg2, 256, 0, stream>>>(q1, (__half*)nullptr, outw, SEGARGS, 3);
        k_scatter<OT><<<ewg, 256, 0, stream>>>(outw, A.dstp, A.h);
    }
#undef SEGARGS

    // ---- LinearBlock ----
    if (bigLB) {
        __half* hf  = (__half*)A.ws_base;
        __half* w1h = hf  + (size_t)N_ * 64;
        __half* w2h = w1h + (size_t)SND_ * 64;
        __half* w3h = w2h + (size_t)SND_ * SND_;
        __half* w4h = w3h + (size_t)SND_ * SND_;
        __half* w5h = w4h + (size_t)SND_ * SND_;
        __half* hb1 = w5h + (size_t)64 * SND_;
        __half* hb2 = hb1 + (size_t)N_ * SND_;
        __half* hb3 = hb2 + (size_t)N_ * SND_;
        __half* hb4 = hb3 + (size_t)N_ * SND_;
        k_f2h<<<(N_ * 64 + 255) / 256, 256, 0, stream>>>(A.h, hf, N_ * 64);
        k_f2h<<<(SND_ * 64 + 255) / 256, 256, 0, stream>>>(A.lb1w, w1h, SND_ * 64);
        k_f2h<<<(SND_ * SND_ + 255) / 256, 256, 0, stream>>>(A.lb2w, w2h, SND_ * SND_);
        k_f2h<<<(SND_ * SND_ + 255) / 256, 256, 0, stream>>>(A.lb3w, w3h, SND_ * SND_);
        k_f2h<<<(SND_ * SND_ + 255) / 256, 256, 0, stream>>>(A.lb4w, w4h, SND_ * SND_);
        k_f2h<<<(SND_ * 64 + 255) / 256, 256, 0, stream>>>(A.lb5w, w5h, 64 * SND_);
        dim3 g6((N_ + 63) / 64, SND_ / 64);
        dim3 g1((N_ + 63) / 64, 1);
        k_gemm_h<0, __half><<<g6, 256, 0, stream>>>(hf,  w1h, A.lb1b, nullptr, hb1, N_, 64,   SND_);
        k_gemm_h<0, __half><<<g6, 256, 0, stream>>>(hb1, w2h, A.lb2b, nullptr, hb2, N_, SND_, SND_);
        k_gemm_h<1, __half><<<g6, 256, 0, stream>>>(hb2, w3h, A.lb3b, hb1,    hb3, N_, SND_, SND_);
        k_gemm_h<1, __half><<<g6, 256, 0, stream>>>(hb3, w4h, A.lb4b, hb3,    hb4, N_, SND_, SND_);
        k_gemm_h<0, float ><<<g1, 256, 0, stream>>>(hb4, w5h, A.lb5b, nullptr, A.h, N_, SND_, 64);
    } else {
        const int CH = 12800;
        size_t cb = (size_t)CH * SND_ * 4;
        float* b1 = (float*)A.ws_base;
        float* b2 = (float*)(A.ws_base + cb);
        float* b3 = (float*)(A.ws_base + 2 * cb);
        for (int r0 = 0; r0 < N_; r0 += CH) {
            int m = (N_ - r0 < CH) ? (N_ - r0) : CH;
            dim3 g6((m + 63) / 64, SND_ / 64);
            dim3 g1((m + 63) / 64, 1);
            k_gemm<0><<<g6, 256, 0, stream>>>(A.h + (ll)r0 * 64, A.lb1w, A.lb1b, nullptr, b1, m, 64,   SND_);
            k_gemm<0><<<g6, 256, 0, stream>>>(b1, A.lb2w, A.lb2b, nullptr, b2, m, SND_, SND_);
            k_gemm<1><<<g6, 256, 0, stream>>>(b2, A.lb3w, A.lb3b, b1,      b3, m, SND_, SND_);
            k_gemm<1><<<g6, 256, 0, stream>>>(b3, A.lb4w, A.lb4b, b3,      b1, m, SND_, SND_);
            k_gemm<0><<<g1, 256, 0, stream>>>(b1, A.lb5w, A.lb5b, nullptr, A.h + (ll)r0 * 64, m, SND_, 64);
        }
    }
}

extern "C" void kernel_launch(void* const* d_in, const int* in_sizes, int n_in,
                              void* d_out, int out_size, void* d_ws, size_t ws_size,
                              hipStream_t stream) {
    (void)in_sizes; (void)n_in; (void)out_size;
    Args A;
    A.x      = (const float*)d_in[0];
    A.ea     = (const float*)d_in[1];
    const int* eidx = (const int*)d_in[2];
    const int* lgp  = (const int*)d_in[3];
    A.eib    = (const int*)d_in[4];
    A.Wu     = (const float*)d_in[5];
    A.Wv     = (const float*)d_in[6];
    A.We     = (const float*)d_in[7];
    A.w_rel  = (const float*)d_in[8];
    A.b_rel  = (const float*)d_in[9];
    A.w_root = (const float*)d_in[10];
    A.a      = (const float*)d_in[11];
    A.Wg     = (const float*)d_in[12];
    A.bg     = (const float*)d_in[13];
    A.abias  = (const float*)d_in[14];
    A.lb1w = (const float*)d_in[15]; A.lb1b = (const float*)d_in[16];
    A.lb2w = (const float*)d_in[17]; A.lb2b = (const float*)d_in[18];
    A.lb3w = (const float*)d_in[19]; A.lb3b = (const float*)d_in[20];
    A.lb4w = (const float*)d_in[21]; A.lb4b = (const float*)d_in[22];
    A.lb5w = (const float*)d_in[23]; A.lb5b = (const float*)d_in[24];
    A.src  = eidx;
    A.dstp = eidx + E_;
    A.lsrc = lgp;
    A.ldst = lgp + ELG_;
    A.h       = (float*)d_out;
    A.ws_base = (char*)d_ws;

    char* p = (char*)d_ws;
    auto alloc = [&](size_t bytes) -> char* {
        char* r = p;
        p += (bytes + 255) & ~(size_t)255;
        return r;
    };
    A.xc     = (float*)alloc((size_t)E_ * 4);
    A.gouts  = (float*)alloc((size_t)B_ * T_ * 64 * 4);
    A.scores = (float*)alloc((size_t)B_ * T_ * 4);
    A.rowptr = (int*)alloc((size_t)(E_ + 1) * 4);
    A.cnt    = (int*)alloc((size_t)E_ * 4);
    A.csr    = (int*)alloc((size_t)ELG_ * 4);
    A.bsum   = (int*)alloc(8192);
    A.bptr   = (int*)alloc((size_t)(B_ + 1) * 4);
    A.xu     = (float*)alloc((size_t)N_ * 64 * 4);
    A.xv     = (float*)alloc((size_t)N_ * 64 * 4);

    const size_t NEED_T1 = 244736768ull;
    const size_t NEED_T3 = 193536768ull;

    if (ws_size < NEED_T3) {
        k_zero<<<(N_ * 64 + 255) / 256, 256, 0, stream>>>((float*)d_out, N_ * 64);
        return;
    }

    hipMemsetAsync(A.cnt, 0, (size_t)E_ * 4, stream);
    k_count<<<(ELG_ + 255) / 256, 256, 0, stream>>>(A.ldst, A.cnt);
    int nb1 = (E_ + 255) / 256;
    k_scan1<<<nb1, 256, 0, stream>>>(A.cnt, A.rowptr, A.bsum);
    k_scan2<<<1, 256, 0, stream>>>(A.bsum, nb1);
    k_scan3<<<nb1, 256, 0, stream>>>(A.rowptr, A.bsum);
    hipMemsetAsync(A.cnt, 0, (size_t)E_ * 4, stream);
    k_fill<<<(ELG_ + 255) / 256, 256, 0, stream>>>(A.lsrc, A.ldst, A.rowptr, A.cnt, A.csr);
    k_bptr<<<(B_ + 1 + 255) / 256, 256, 0, stream>>>(A.eib, A.bptr);

    if (ws_size >= NEED_T1) {
        float* bufA = (float*)alloc((size_t)E_ * 64 * 4);
        float* bufB = (float*)alloc((size_t)E_ * 64 * 4);
        // 4 f16 state slots aliased over bufA/bufB (o6/o5 consumed by k_scat2 first)
        __half* q0 = (__half*)bufA;
        __half* q1 = q0 + (size_t)E_ * 64;
        __half* q2 = (__half*)bufB;
        __half* q3 = q2 + (size_t)E_ * 64;
        run_tier<float, float>(A, bufA, bufB, q0, q1, q2, q3, (float*)nullptr, true, stream);
    } else {
        __half* bufA = (__half*)alloc((size_t)E_ * 64 * 2);
        __half* bufB = (__half*)alloc((size_t)E_ * 64 * 2);
        __half* outw = (__half*)alloc((size_t)E_ * 64 * 2);
        run_tier<__half, __half>(A, bufA, bufB, bufA, bufB, (__half*)nullptr, (__half*)nullptr,
                                 outw, false, stream);
    }
}